// Round 8
// baseline (198.736 us; speedup 1.0000x reference)
//
#include <hip/hip_runtime.h>
#include <hip/hip_bf16.h>

// Problem constants: B=2, S=2048, H=16, dk=64, D_MODEL=1024, THETA=10000
// Packed fragment layouts (round 7, kept):
//   Qf/Kf[bh][t][j][lane][e]  = X[bh][t*32 + (lane&31)][j*16 + (lane>>5)*8 + e]
//   Vf[bh][t][seg][lane][e]   = V[bh][t*32 + (seg&1)*16 + (lane>>5)*8 + e][(seg>>1)*32 + (lane&31)]
// Round 8: QKV GEMM -> 256x256 8-phase counted-vmcnt schedule (T2+T3+T4+T5).

using u16 = unsigned short;
typedef __attribute__((ext_vector_type(8))) short short8;
typedef __attribute__((ext_vector_type(4))) float f32x4;
typedef __attribute__((ext_vector_type(16))) float f32x16;
typedef __attribute__((ext_vector_type(2))) unsigned uint2v;
typedef __attribute__((ext_vector_type(4))) unsigned uint4v;

__device__ __forceinline__ float bf2f(u16 v) {
  unsigned u = ((unsigned)v) << 16; float f; __builtin_memcpy(&f, &u, 4); return f;
}
__device__ __forceinline__ u16 f2bf(float f) {
  unsigned u; __builtin_memcpy(&u, &f, 4);
  return (u16)((u + 0x7fffu + ((u >> 16) & 1u)) >> 16);
}
__device__ __forceinline__ float u2f(unsigned u) {
  float f; __builtin_memcpy(&f, &u, 4); return f;
}
__device__ __forceinline__ unsigned f2u(float f) {
  unsigned u; __builtin_memcpy(&u, &f, 4); return u;
}
__device__ __forceinline__ float xhalf_max(float x) {
  uint2v s = __builtin_amdgcn_permlane32_swap(f2u(x), f2u(x), false, false);
  unsigned ax = s.x, bx = s.y;
  return fmaxf(u2f(ax), u2f(bx));
}
__device__ __forceinline__ float xhalf_sum(float x) {
  uint2v s = __builtin_amdgcn_permlane32_swap(f2u(x), f2u(x), false, false);
  unsigned ax = s.x, bx = s.y;
  return u2f(ax) + u2f(bx);
}

__device__ __forceinline__ void gload_lds16(const void* g, void* l) {
  __builtin_amdgcn_global_load_lds((const __attribute__((address_space(1))) unsigned*)g,
                                   (__attribute__((address_space(3))) unsigned*)l, 16, 0, 0);
}

// ---------------- fused fp32 -> bf16 convert for x, W_qkv, W_o ----------------
__global__ __launch_bounds__(256) void cvt_all(const float* __restrict__ x, const float* __restrict__ wqkv,
                                               const float* __restrict__ wo, u16* __restrict__ xb,
                                               u16* __restrict__ wqkvb, u16* __restrict__ wob) {
  int i = blockIdx.x * 256 + threadIdx.x;  // 2M quads total
  const float* src; u16* dst; int off;
  if (i < 1048576) { src = x; dst = xb; off = i; }
  else if (i < 1048576 + 786432) { src = wqkv; dst = wqkvb; off = i - 1048576; }
  else { src = wo; dst = wob; off = i - (1048576 + 786432); }
  float4 v = *(const float4*)(src + (size_t)off * 4);
  unsigned lo = f2bf(v.x) | ((unsigned)f2bf(v.y) << 16);
  unsigned hi = f2bf(v.z) | ((unsigned)f2bf(v.w) << 16);
  uint2 w; w.x = lo; w.y = hi;
  *(uint2*)(dst + (size_t)off * 4) = w;
}

// ---------------- QKV GEMM: 256x256 tile, BK=64 (2 K-halves), 8-phase schedule ----------------
// C[4096,3072] = A[4096,1024] * B[3072,1024]^T, bf16 in/out, fp32 acc.
// LDS: [buf(2)][A/B(2)][khalf(2)][256 rows][32 k] bf16 = 128 KiB (dynamic).
// Swizzle: 16B slot s at row r stored at physical slot s^(r&3) (involution; applied
// on stage-source AND read). Raw s_barrier (no vmcnt drain); vmcnt(4) at ph4/ph8 only.
#define HBASE(b, ab, kh) (lds + ((((b) * 2 + (ab)) * 2 + (kh)) << 13))
#define STAGE(b, ab, kh, kt) do {                                                     \
    const u16* _src = (ab) ? Bm : A;                                                  \
    const int _r0 = (ab) ? n0 : m0;                                                   \
    u16* _hb = HBASE(b, ab, kh) + (wid << 9);                                         \
    _Pragma("unroll")                                                                 \
    for (int _rd = 0; _rd < 2; ++_rd) {                                               \
      int _pp = (wid << 6) + lane + _rd * 512;                                        \
      int _r = _pp >> 2;                                                              \
      int _ls = (_pp & 3) ^ (_r & 3);                                                 \
      gload_lds16(_src + (size_t)(_r0 + _r) * 1024 + ((kt) << 6) + ((kh) << 5) + (_ls << 3), \
                  _hb + _rd * 4096);                                                  \
    } } while (0)
#define PH(b, kk, nh, sb, sab, skh, skt, dovm) do {                                   \
    const u16* _Ab = HBASE(b, 0, kk);                                                 \
    const u16* _Bb = HBASE(b, 1, kk);                                                 \
    short8 _a[8], _bv[2];                                                             \
    _Pragma("unroll")                                                                 \
    for (int _mf = 0; _mf < 8; ++_mf) {                                               \
      int _r = (wr << 7) + _mf * 16 + fr;                                             \
      _a[_mf] = *(const short8*)(_Ab + _r * 32 + ((fk ^ (_r & 3)) << 3));             \
    }                                                                                 \
    _Pragma("unroll")                                                                 \
    for (int _i = 0; _i < 2; ++_i) {                                                  \
      int _r = (wc << 6) + ((nh) * 2 + _i) * 16 + fr;                                 \
      _bv[_i] = *(const short8*)(_Bb + _r * 32 + ((fk ^ (_r & 3)) << 3));             \
    }                                                                                 \
    STAGE(sb, sab, skh, skt);                                                         \
    asm volatile("s_barrier" ::: "memory");                                           \
    __builtin_amdgcn_s_setprio(1);                                                    \
    _Pragma("unroll")                                                                 \
    for (int _mf = 0; _mf < 8; ++_mf) {                                               \
      acc[_mf][(nh) * 2 + 0] = __builtin_amdgcn_mfma_f32_16x16x32_bf16(_a[_mf], _bv[0], acc[_mf][(nh) * 2 + 0], 0, 0, 0); \
      acc[_mf][(nh) * 2 + 1] = __builtin_amdgcn_mfma_f32_16x16x32_bf16(_a[_mf], _bv[1], acc[_mf][(nh) * 2 + 1], 0, 0, 0); \
    }                                                                                 \
    __builtin_amdgcn_s_setprio(0);                                                    \
    if (dovm) asm volatile("s_waitcnt vmcnt(4)" ::: "memory");                        \
    asm volatile("s_barrier" ::: "memory");                                           \
  } while (0)

__global__ __launch_bounds__(512, 2) void gemm_qkv_8ph(const u16* __restrict__ A,
                                                       const u16* __restrict__ Bm,
                                                       u16* __restrict__ C) {
  extern __shared__ u16 lds[];
  const int tid = threadIdx.x;
  const int lane = tid & 63;
  const int wid = tid >> 6;
  const int wr = wid >> 2;   // 2 M-waves
  const int wc = wid & 3;    // 4 N-waves
  const int fr = lane & 15;
  const int fk = lane >> 4;
  // bijective XCD swizzle: 192 wgs = 8 XCDs x 24
  const int wg = blockIdx.x;
  const int swz = (wg & 7) * 24 + (wg >> 3);
  const int m0 = (swz & 15) << 8;
  const int n0 = (swz >> 4) << 8;

  f32x4 acc[8][4];
#pragma unroll
  for (int mf = 0; mf < 8; ++mf)
#pragma unroll
    for (int nf = 0; nf < 4; ++nf) acc[mf][nf] = (f32x4){0.f, 0.f, 0.f, 0.f};

  // prologue: X_0 fully + Y_0 kh0; vmcnt(4) -> X landed, Y kh0 may fly
  STAGE(0, 0, 0, 0); STAGE(0, 1, 0, 0); STAGE(0, 0, 1, 0); STAGE(0, 1, 1, 0);
  STAGE(1, 0, 0, 1); STAGE(1, 1, 0, 1);
  asm volatile("s_waitcnt vmcnt(4)" ::: "memory");
  asm volatile("s_barrier" ::: "memory");

  // 8 iterations x 2 K-tiles (K=1024, BK=64 -> 16 tiles)
  for (int n = 0; n < 8; ++n) {
    const int ktY = 2 * n + 1;
    int ktX2 = 2 * n + 2; if (ktX2 > 15) ktX2 = 15;
    int ktY2 = 2 * n + 3; if (ktY2 > 15) ktY2 = 15;
    // free/landing discipline: slot staged >=2 checkpoints before its first read
    PH(0, 0, 0, 1, 0, 1, ktY,  false);  // ph1: compute X kh0/nh0; stage Y A kh1 (this iter's Y)
    PH(0, 0, 1, 1, 1, 1, ktY,  false);  // ph2: stage Y B kh1
    PH(0, 1, 0, 0, 0, 0, ktX2, false);  // ph3: stage X' A kh0
    PH(0, 1, 1, 0, 1, 0, ktX2, true);   // ph4: stage X' B kh0; vmcnt(4)
    PH(1, 0, 0, 0, 0, 1, ktX2, false);  // ph5: stage X' A kh1
    PH(1, 0, 1, 0, 1, 1, ktX2, false);  // ph6: stage X' B kh1
    PH(1, 1, 0, 1, 0, 0, ktY2, false);  // ph7: stage Y' A kh0
    PH(1, 1, 1, 1, 1, 0, ktY2, true);   // ph8: stage Y' B kh0; vmcnt(4)
  }

  // epilogue
#pragma unroll
  for (int mf = 0; mf < 8; ++mf)
#pragma unroll
    for (int nf = 0; nf < 4; ++nf)
#pragma unroll
      for (int j = 0; j < 4; ++j) {
        int row = m0 + (wr << 7) + mf * 16 + fk * 4 + j;
        int col = n0 + (wc << 6) + nf * 16 + fr;
        C[(size_t)row * 3072 + col] = f2bf(acc[mf][nf][j]);
      }
}
#undef PH
#undef STAGE
#undef HBASE

// ---------------- GEMM 64x128 (occupancy variant, O-projection) ----------------
template <typename OutT>
__global__ __launch_bounds__(256) void gemm_bt64(const u16* __restrict__ A, const u16* __restrict__ B,
                                                 OutT* __restrict__ C, int M, int N, int K) {
  __shared__ u16 As[64 * 32];   // 4 KB
  __shared__ u16 Bs[128 * 32];  // 8 KB
  const int tid = threadIdx.x;
  const int wave = tid >> 6;
  const int lane = tid & 63;
  const int m0 = blockIdx.x * 64;
  const int n0 = blockIdx.y * 128;
  const int wm = (wave >> 1) * 32;
  const int wn = (wave & 1) * 64;

  f32x4 acc[2][4];
#pragma unroll
  for (int m = 0; m < 2; ++m)
#pragma unroll
    for (int n = 0; n < 4; ++n) acc[m][n] = (f32x4){0.f, 0.f, 0.f, 0.f};

  const int srow = lane >> 2;
  const int scol = (lane & 3) * 8;
  const u16* Ag = A + (size_t)(m0 + wave * 16 + srow) * K + scol;
  const u16* Bg0 = B + (size_t)(n0 + wave * 16 + srow) * K + scol;
  const u16* Bg1 = B + (size_t)(n0 + 64 + wave * 16 + srow) * K + scol;
  u16* AsW = As + (wave * 16) * 32;
  u16* BsW0 = Bs + (wave * 16) * 32;
  u16* BsW1 = Bs + (64 + wave * 16) * 32;

  const int fr = lane & 15;
  const int fk = (lane >> 4) * 8;

  for (int k0 = 0; k0 < K; k0 += 32) {
    __syncthreads();
    gload_lds16(Ag + k0, AsW);
    gload_lds16(Bg0 + k0, BsW0);
    gload_lds16(Bg1 + k0, BsW1);
    __syncthreads();

    short8 af[2], bf[4];
#pragma unroll
    for (int m = 0; m < 2; ++m)
      af[m] = *(const short8*)(As + (wm + m * 16 + fr) * 32 + fk);
#pragma unroll
    for (int n = 0; n < 4; ++n)
      bf[n] = *(const short8*)(Bs + (wn + n * 16 + fr) * 32 + fk);
#pragma unroll
    for (int m = 0; m < 2; ++m)
#pragma unroll
      for (int n = 0; n < 4; ++n)
        acc[m][n] = __builtin_amdgcn_mfma_f32_16x16x32_bf16(af[m], bf[n], acc[m][n], 0, 0, 0);
  }

  const int fg = lane >> 4;
#pragma unroll
  for (int m = 0; m < 2; ++m)
#pragma unroll
    for (int n = 0; n < 4; ++n)
#pragma unroll
      for (int r = 0; r < 4; ++r) {
        int row = m0 + wm + m * 16 + fg * 4 + r;
        int col = n0 + wn + n * 16 + fr;
        if constexpr (sizeof(OutT) == 2)
          C[(size_t)row * N + col] = (OutT)f2bf(acc[m][n][r]);
        else
          C[(size_t)row * N + col] = (OutT)acc[m][n][r];
      }
}

// ---------------- RoPE: qkv -> Qf,Kf packed fragment layout; Q pre-scaled 0.125*log2(e) ----------------
__global__ __launch_bounds__(256) void rope_qk(const u16* __restrict__ qkv, const int* __restrict__ pos,
                                               u16* __restrict__ Qf, u16* __restrict__ Kf) {
  int t = blockIdx.x * 256 + threadIdx.x;
  int i = t & 31;          // d0 = 2i
  int h = (t >> 5) & 15;
  int s = (t >> 9) & 2047;
  int b = t >> 20;
  float p = (float)pos[(b << 11) + s];
  float ang = p * __builtin_exp2f(-(float)i * 0.41524101186f);
  float sn, cs;
  sincosf(ang, &sn, &cs);
  const u16* base = qkv + ((size_t)((b << 11) + s)) * 3072 + h * 64 + 2 * i;
  float qe = bf2f(base[0]), qo = bf2f(base[1]);
  float ke = bf2f(base[1024]), ko = bf2f(base[1025]);
  const float QS = 0.18033688011112043f;  // 0.125 * log2(e)
  unsigned qw = f2bf((cs * qe - sn * qo) * QS) | ((unsigned)f2bf((sn * qe + cs * qo) * QS) << 16);
  unsigned kw = f2bf(cs * ke - sn * ko) | ((unsigned)f2bf(sn * ke + cs * ko) << 16);
  int bh = (b << 4) + h;
  int d0 = 2 * i;
  int tile = s >> 5;
  int l = (s & 31) + 32 * ((d0 >> 3) & 1);
  int j = d0 >> 4;
  int e = d0 & 7;
  size_t o = ((((size_t)bh * 64 + tile) * 4 + j) * 64 + l) * 8 + e;
  *(unsigned*)(Qf + o) = qw;
  *(unsigned*)(Kf + o) = kw;
}

// ---------------- V pack: qkv V-part -> Vf packed fragment layout ----------------
__global__ __launch_bounds__(256) void v_pack(const u16* __restrict__ qkv, u16* __restrict__ Vf) {
  __shared__ u16 lds[64][72];  // [s_local][d], padded
  const int bh = blockIdx.y;
  const int b = bh >> 4, h = bh & 15;
  const int s0 = blockIdx.x * 64;
  const int t = threadIdx.x;
  {
    const int r = t >> 3;
    const int c = t & 7;
#pragma unroll
    for (int p = 0; p < 2; ++p) {
      int s = r + p * 32;
      const u16* src = qkv + ((size_t)((b << 11) + s0 + s)) * 3072 + 2048 + h * 64 + c * 8;
      *(uint4*)&lds[s][c * 8] = *(const uint4*)src;
    }
  }
  __syncthreads();
#pragma unroll
  for (int p = 0; p < 2; ++p) {
    int item = t + p * 256;
    int tt = item >> 8;
    int seg = (item >> 6) & 3;
    int l = item & 63;
    int d = (seg >> 1) * 32 + (l & 31);
    int sb = tt * 32 + (seg & 1) * 16 + (l >> 5) * 8;
    u16 tmp[8];
#pragma unroll
    for (int e = 0; e < 8; ++e) tmp[e] = lds[sb + e][d];
    int kt = (s0 >> 5) + tt;
    size_t o = ((((size_t)bh * 64 + kt) * 4 + seg) * 64 + l) * 8;
    *(uint4*)(Vf + o) = *(uint4*)tmp;
  }
}

// ---------------- causal flash attention v6: packed-fragment coalesced loads ----------------
__global__ __launch_bounds__(256, 2) void attn6(const u16* __restrict__ Qf, const u16* __restrict__ Kf,
                                                const u16* __restrict__ Vf, u16* __restrict__ Ao) {
  __shared__ float smM[3][64], smL[3][64];
  __shared__ float smO[3][64][33];
  const int tid = threadIdx.x;
  const int lane = tid & 63;
  const int wid = tid >> 6;
  const int bid = blockIdx.x;            // 2048 = 8 xcd * 4 bh * 64 qt
  const int xcd = bid & 7;
  const int rr = bid >> 3;
  const int bh = xcd * 4 + (rr & 3);
  const int qt = 63 - (rr >> 2);
  const int q0 = qt * 32;
  const u16* __restrict__ Qp = Qf + (size_t)bh * 131072;
  const u16* __restrict__ Kp = Kf + (size_t)bh * 131072;
  const u16* __restrict__ Vp = Vf + (size_t)bh * 131072;
  const int lq = lane & 31;
  const int hi = lane >> 5;

  const u16* qb = Qp + (size_t)qt * 2048 + lane * 8;
  short8 qf0 = *(const short8*)(qb);
  short8 qf1 = *(const short8*)(qb + 512);
  short8 qf2 = *(const short8*)(qb + 1024);
  short8 qf3 = *(const short8*)(qb + 1536);

  f32x16 o0, o1;
#pragma unroll
  for (int r = 0; r < 16; ++r) { o0[r] = 0.f; o1[r] = 0.f; }
  float m = -1e30f, lsum = 0.f;

  const int nkt = qt + 1;
  const int base = nkt >> 2, rem = nkt & 3;
  const int cnt = base + (wid < rem ? 1 : 0);
  const int beg = wid * base + (wid < rem ? wid : rem);

  if (cnt > 0) {
    const u16* kp = Kp + (size_t)beg * 2048 + lane * 8;
    const u16* vp = Vp + (size_t)beg * 2048 + lane * 8;
    short8 kc0 = *(const short8*)(kp);
    short8 kc1 = *(const short8*)(kp + 512);
    short8 kc2 = *(const short8*)(kp + 1024);
    short8 kc3 = *(const short8*)(kp + 1536);
    short8 vc0 = *(const short8*)(vp);
    short8 vc1 = *(const short8*)(vp + 512);
    short8 vc2 = *(const short8*)(vp + 1024);
    short8 vc3 = *(const short8*)(vp + 1536);

    for (int i = 0; i < cnt; ++i) {
      const int kt = beg + i;
      const int ktn = beg + (i + 1 < cnt ? i + 1 : i);
      const u16* kpn = Kp + (size_t)ktn * 2048 + lane * 8;
      const u16* vpn = Vp + (size_t)ktn * 2048 + lane * 8;
      short8 kn0 = *(const short8*)(kpn);
      short8 kn1 = *(const short8*)(kpn + 512);
      short8 kn2 = *(const short8*)(kpn + 1024);
      short8 kn3 = *(const short8*)(kpn + 1536);
      short8 vn0 = *(const short8*)(vpn);
      short8 vn1 = *(const short8*)(vpn + 512);
      short8 vn2 = *(const short8*)(vpn + 1024);
      short8 vn3 = *(const short8*)(vpn + 1536);

      f32x16 sc;
#pragma unroll
      for (int r = 0; r < 16; ++r) sc[r] = 0.f;
      sc = __builtin_amdgcn_mfma_f32_32x32x16_bf16(kc0, qf0, sc, 0, 0, 0);
      sc = __builtin_amdgcn_mfma_f32_32x32x16_bf16(kc1, qf1, sc, 0, 0, 0);
      sc = __builtin_amdgcn_mfma_f32_32x32x16_bf16(kc2, qf2, sc, 0, 0, 0);
      sc = __builtin_amdgcn_mfma_f32_32x32x16_bf16(kc3, qf3, sc, 0, 0, 0);

      if (kt == qt) {
#pragma unroll
        for (int r = 0; r < 16; ++r) {
          int ko = (r & 3) + 8 * (r >> 2) + 4 * hi;
          sc[r] = (ko <= lq) ? sc[r] : -1e30f;
        }
      }

      float t0 = fmaxf(fmaxf(sc[0], sc[1]), sc[2]);
      float t1 = fmaxf(fmaxf(sc[3], sc[4]), sc[5]);
      float t2 = fmaxf(fmaxf(sc[6], sc[7]), sc[8]);
      float t3 = fmaxf(fmaxf(sc[9], sc[10]), sc[11]);
      float t4 = fmaxf(fmaxf(sc[12], sc[13]), sc[14]);
      float t5 = fmaxf(fmaxf(t0, t1), sc[15]);
      float t6 = fmaxf(fmaxf(t2, t3), t4);
      float pmax = xhalf_max(fmaxf(t5, t6));

      if (!__all(pmax - m <= 11.5f)) {
        float nm = fmaxf(m, pmax);
        float alpha = __builtin_exp2f(m - nm);
        lsum *= alpha;
#pragma unroll
        for (int r = 0; r < 16; ++r) { o0[r] *= alpha; o1[r] *= alpha; }
        m = nm;
      }

#pragma unroll
      for (int r = 0; r < 16; ++r) sc[r] = __builtin_exp2f(sc[r] - m);
      float r8[8];
#pragma unroll
      for (int r = 0; r < 8; ++r) r8[r] = sc[r] + sc[r + 8];
#pragma unroll
      for (int s = 4; s >= 1; s >>= 1)
#pragma unroll
        for (int r = 0; r < s; ++r) r8[r] += r8[r + s];
      lsum += xhalf_sum(r8[0]);

      unsigned w[8];
#pragma unroll
      for (int t = 0; t < 8; ++t) {
        unsigned d;
        asm("v_cvt_pk_bf16_f32 %0, %1, %2" : "=v"(d) : "v"(sc[2 * t]), "v"(sc[2 * t + 1]));
        w[t] = d;
      }
      short8 pb0, pb1;
      {
        uint2v r1 = __builtin_amdgcn_permlane32_swap(w[0], w[2], false, false);
        uint2v r2 = __builtin_amdgcn_permlane32_swap(w[1], w[3], false, false);
        unsigned r1x = r1.x, r1y = r1.y, r2x = r2.x, r2y = r2.y;
        uint4v t4v; t4v.x = r1x; t4v.y = r2x; t4v.z = r1y; t4v.w = r2y;
        pb0 = __builtin_bit_cast(short8, t4v);
        uint2v r3 = __builtin_amdgcn_permlane32_swap(w[4], w[6], false, false);
        uint2v r4 = __builtin_amdgcn_permlane32_swap(w[5], w[7], false, false);
        unsigned r3x = r3.x, r3y = r3.y, r4x = r4.x, r4y = r4.y;
        uint4v t5v; t5v.x = r3x; t5v.y = r4x; t5v.z = r3y; t5v.w = r4y;
        pb1 = __builtin_bit_cast(short8, t5v);
      }

      o0 = __builtin_amdgcn_mfma_f32_32x32x16_bf16(vc0, pb0, o0, 0, 0, 0);
      o0 = __builtin_amdgcn_mfma_f32_32x32x16_bf16(vc1, pb1, o0, 0, 0, 0);
      o1 = __builtin_amdgcn_mfma_f32_32x32x16_bf16(vc2, pb0, o1, 0, 0, 0);
      o1 = __builtin_amdgcn_mfma_f32_32x32x16_bf16(vc3, pb1, o1, 0, 0, 0);

      kc0 = kn0; kc1 = kn1; kc2 = kn2; kc3 = kn3;
      vc0 = vn0; vc1 = vn1; vc2 = vn2; vc3 = vn3;
    }
  }

  if (wid != 0) {
    smM[wid - 1][lane] = m;
    smL[wid - 1][lane] = lsum;
#pragma unroll
    for (int r = 0; r < 16; ++r) smO[wid - 1][lane][r] = o0[r];
#pragma unroll
    for (int r = 0; r < 16; ++r) smO[wid - 1][lane][16 + r] = o1[r];
  }
  __syncthreads();
  if (wid == 0) {
    float m1 = smM[0][lane], m2 = smM[1][lane], m3 = smM[2][lane];
    float M = fmaxf(fmaxf(m, m1), fmaxf(m2, m3));
    float a0 = __builtin_exp2f(m - M);
    float a1 = __builtin_exp2f(m1 - M);
    float a2 = __builtin_exp2f(m2 - M);
    float a3 = __builtin_exp2f(m3 - M);
    float L = lsum * a0 + smL[0][lane] * a1 + smL[1][lane] * a2 + smL[2][lane] * a3;
    float inv = 1.f / L;
    const int b = bh >> 4, h = bh & 15;
    u16* outp = Ao + ((size_t)(b << 11) + q0 + lq) * 1024 + h * 64;
#pragma unroll
    for (int g = 0; g < 4; ++g) {
      int d = 8 * g + 4 * hi;
      float c[8];
#pragma unroll
      for (int j = 0; j < 4; ++j) {
        c[j] = (o0[4 * g + j] * a0 + smO[0][lane][4 * g + j] * a1 +
                smO[1][lane][4 * g + j] * a2 + smO[2][lane][4 * g + j] * a3) * inv;
        c[4 + j] = (o1[4 * g + j] * a0 + smO[0][lane][16 + 4 * g + j] * a1 +
                    smO[1][lane][16 + 4 * g + j] * a2 + smO[2][lane][16 + 4 * g + j] * a3) * inv;
      }
      uint2v w0;
      w0.x = f2bf(c[0]) | ((unsigned)f2bf(c[1]) << 16);
      w0.y = f2bf(c[2]) | ((unsigned)f2bf(c[3]) << 16);
      *(uint2v*)(outp + d) = w0;
      uint2v w1;
      w1.x = f2bf(c[4]) | ((unsigned)f2bf(c[5]) << 16);
      w1.y = f2bf(c[6]) | ((unsigned)f2bf(c[7]) << 16);
      *(uint2v*)(outp + 32 + d) = w1;
    }
  }
}

extern "C" void kernel_launch(void* const* d_in, const int* in_sizes, int n_in,
                              void* d_out, int out_size, void* d_ws, size_t ws_size,
                              hipStream_t stream) {
  const float* x = (const float*)d_in[0];
  const int* pos = (const int*)d_in[1];
  const float* Wqkv = (const float*)d_in[2];
  const float* Wo = (const float*)d_in[3];
  float* out = (float*)d_out;

  char* ws = (char*)d_ws;
  const size_t MB = 1024 * 1024;
  u16* xb     = (u16*)(ws);             //  8 MB: [4096,1024]
  u16* wqkvb  = (u16*)(ws + 8 * MB);    //  6 MB: [3072,1024]
  u16* wob    = (u16*)(ws + 14 * MB);   //  2 MB: [1024,1024]
  u16* qkv    = (u16*)(ws + 16 * MB);   // 24 MB: [4096,3072]
  u16* Qf     = (u16*)(ws + 40 * MB);   //  8 MB packed fragments (pre-scaled 0.125*log2e)
  u16* Kf     = (u16*)(ws + 48 * MB);   //  8 MB packed fragments
  u16* Vf     = (u16*)(ws + 56 * MB);   //  8 MB packed fragments
  u16* ao     = (u16*)(ws + 64 * MB);   //  8 MB: [4096,1024]

  // allow 128 KiB dynamic LDS for the 8-phase GEMM (idempotent; ignore errors)
  (void)hipFuncSetAttribute((const void*)gemm_qkv_8ph,
                            hipFuncAttributeMaxDynamicSharedMemorySize, 131072);

  cvt_all<<<8192, 256, 0, stream>>>(x, Wqkv, Wo, xb, wqkvb, wob);
  gemm_qkv_8ph<<<192, 512, 131072, stream>>>(xb, wqkvb, qkv);
  rope_qk<<<8192, 256, 0, stream>>>(qkv, pos, Qf, Kf);
  v_pack<<<dim3(32, 32), 256, 0, stream>>>(qkv, Vf);
  attn6<<<2048, 256, 0, stream>>>(Qf, Kf, Vf, ao);
  gemm_bt64<float><<<dim3(64, 8), 256, 0, stream>>>(ao, wob, out, 4096, 1024, 1024);
}

// Round 9
// 179.289 us; speedup vs baseline: 1.1085x; 1.1085x over previous
//
#include <hip/hip_runtime.h>
#include <hip/hip_bf16.h>

// Problem constants: B=2, S=2048, H=16, dk=64, D_MODEL=1024, THETA=10000
// Packed fragment layouts (round 7, kept):
//   Qf/Kf[bh][t][j][lane][e]  = X[bh][t*32 + (lane&31)][j*16 + (lane>>5)*8 + e]
//   Vf[bh][t][seg][lane][e]   = V[bh][t*32 + (seg&1)*16 + (lane>>5)*8 + e][(seg>>1)*32 + (lane&31)]
// Round 9: revert 8-phase; GEMMs -> BK=64 + slot^(row&7) XOR swizzle (both-sides:
// pre-swizzled gload_lds source + swizzled ds_read). rope -> 16B frag per thread.

using u16 = unsigned short;
typedef __attribute__((ext_vector_type(8))) short short8;
typedef __attribute__((ext_vector_type(4))) float f32x4;
typedef __attribute__((ext_vector_type(16))) float f32x16;
typedef __attribute__((ext_vector_type(2))) unsigned uint2v;
typedef __attribute__((ext_vector_type(4))) unsigned uint4v;

__device__ __forceinline__ float bf2f(u16 v) {
  unsigned u = ((unsigned)v) << 16; float f; __builtin_memcpy(&f, &u, 4); return f;
}
__device__ __forceinline__ u16 f2bf(float f) {
  unsigned u; __builtin_memcpy(&u, &f, 4);
  return (u16)((u + 0x7fffu + ((u >> 16) & 1u)) >> 16);
}
__device__ __forceinline__ float u2f(unsigned u) {
  float f; __builtin_memcpy(&f, &u, 4); return f;
}
__device__ __forceinline__ unsigned f2u(float f) {
  unsigned u; __builtin_memcpy(&u, &f, 4); return u;
}
__device__ __forceinline__ float xhalf_max(float x) {
  uint2v s = __builtin_amdgcn_permlane32_swap(f2u(x), f2u(x), false, false);
  unsigned ax = s.x, bx = s.y;
  return fmaxf(u2f(ax), u2f(bx));
}
__device__ __forceinline__ float xhalf_sum(float x) {
  uint2v s = __builtin_amdgcn_permlane32_swap(f2u(x), f2u(x), false, false);
  unsigned ax = s.x, bx = s.y;
  return u2f(ax) + u2f(bx);
}

__device__ __forceinline__ void gload_lds16(const void* g, void* l) {
  __builtin_amdgcn_global_load_lds((const __attribute__((address_space(1))) unsigned*)g,
                                   (__attribute__((address_space(3))) unsigned*)l, 16, 0, 0);
}

// ---------------- fused fp32 -> bf16 convert for x, W_qkv, W_o ----------------
__global__ __launch_bounds__(256) void cvt_all(const float* __restrict__ x, const float* __restrict__ wqkv,
                                               const float* __restrict__ wo, u16* __restrict__ xb,
                                               u16* __restrict__ wqkvb, u16* __restrict__ wob) {
  int i = blockIdx.x * 256 + threadIdx.x;  // 2M quads total
  const float* src; u16* dst; int off;
  if (i < 1048576) { src = x; dst = xb; off = i; }
  else if (i < 1048576 + 786432) { src = wqkv; dst = wqkvb; off = i - 1048576; }
  else { src = wo; dst = wob; off = i - (1048576 + 786432); }
  float4 v = *(const float4*)(src + (size_t)off * 4);
  unsigned lo = f2bf(v.x) | ((unsigned)f2bf(v.y) << 16);
  unsigned hi = f2bf(v.z) | ((unsigned)f2bf(v.w) << 16);
  uint2 w; w.x = lo; w.y = hi;
  *(uint2*)(dst + (size_t)off * 4) = w;
}

// ---------------- GEMM 128x128, BK=64, XOR-swizzled LDS ----------------
// LDS row = 128B = 8 x 16B slots. Logical k-slot s of row r lives at physical
// slot s^(r&7): staged via pre-swizzled global source (gload dest stays linear),
// read back with the same XOR. 16 lanes/frag -> 8 slot groups x 2 rows = 2-way (free).
template <typename OutT>
__global__ __launch_bounds__(256) void gemm_bt2(const u16* __restrict__ A, const u16* __restrict__ B,
                                                OutT* __restrict__ C, int M, int N, int K) {
  __shared__ u16 As[128 * 64];  // 16 KB
  __shared__ u16 Bs[128 * 64];  // 16 KB
  const int tid = threadIdx.x;
  const int wave = tid >> 6;
  const int lane = tid & 63;
  const int m0 = blockIdx.x * 128;
  const int n0 = blockIdx.y * 128;
  const int wm = (wave >> 1) * 64;
  const int wn = (wave & 1) * 64;

  f32x4 acc[4][4];
#pragma unroll
  for (int m = 0; m < 4; ++m)
#pragma unroll
    for (int n = 0; n < 4; ++n) acc[m][n] = (f32x4){0.f, 0.f, 0.f, 0.f};

  const int srow = lane >> 3;   // 0..7 rows per issue
  const int sslot = lane & 7;   // physical 16B slot
  const int fr = lane & 15;
  const int fk = lane >> 4;     // 0..3

  for (int k0 = 0; k0 < K; k0 += 64) {
    __syncthreads();
#pragma unroll
    for (int q = 0; q < 4; ++q) {
      int r = wave * 32 + q * 8 + srow;
      int src_slot = sslot ^ (r & 7);
      gload_lds16(A + (size_t)(m0 + r) * K + k0 + src_slot * 8, As + r * 64 + sslot * 8);
      gload_lds16(B + (size_t)(n0 + r) * K + k0 + src_slot * 8, Bs + r * 64 + sslot * 8);
    }
    __syncthreads();

#pragma unroll
    for (int kk = 0; kk < 2; ++kk) {
      short8 af[4], bf[4];
#pragma unroll
      for (int m = 0; m < 4; ++m) {
        int r = wm + m * 16 + fr;
        af[m] = *(const short8*)(As + r * 64 + (((kk * 4 + fk) ^ (r & 7)) << 3));
      }
#pragma unroll
      for (int n = 0; n < 4; ++n) {
        int r = wn + n * 16 + fr;
        bf[n] = *(const short8*)(Bs + r * 64 + (((kk * 4 + fk) ^ (r & 7)) << 3));
      }
#pragma unroll
      for (int m = 0; m < 4; ++m)
#pragma unroll
        for (int n = 0; n < 4; ++n)
          acc[m][n] = __builtin_amdgcn_mfma_f32_16x16x32_bf16(af[m], bf[n], acc[m][n], 0, 0, 0);
    }
  }

  const int fg = lane >> 4;
#pragma unroll
  for (int m = 0; m < 4; ++m)
#pragma unroll
    for (int n = 0; n < 4; ++n)
#pragma unroll
      for (int r = 0; r < 4; ++r) {
        int row = m0 + wm + m * 16 + fg * 4 + r;
        int col = n0 + wn + n * 16 + fr;
        if constexpr (sizeof(OutT) == 2)
          C[(size_t)row * N + col] = (OutT)f2bf(acc[m][n][r]);
        else
          C[(size_t)row * N + col] = (OutT)acc[m][n][r];
      }
}

// ---------------- GEMM 64x128, BK=64, XOR-swizzled (O-projection) ----------------
template <typename OutT>
__global__ __launch_bounds__(256) void gemm_bt64_2(const u16* __restrict__ A, const u16* __restrict__ B,
                                                   OutT* __restrict__ C, int M, int N, int K) {
  __shared__ u16 As[64 * 64];    // 8 KB
  __shared__ u16 Bs[128 * 64];   // 16 KB
  const int tid = threadIdx.x;
  const int wave = tid >> 6;
  const int lane = tid & 63;
  const int m0 = blockIdx.x * 64;
  const int n0 = blockIdx.y * 128;
  const int wm = (wave >> 1) * 32;
  const int wn = (wave & 1) * 64;

  f32x4 acc[2][4];
#pragma unroll
  for (int m = 0; m < 2; ++m)
#pragma unroll
    for (int n = 0; n < 4; ++n) acc[m][n] = (f32x4){0.f, 0.f, 0.f, 0.f};

  const int srow = lane >> 3;
  const int sslot = lane & 7;
  const int fr = lane & 15;
  const int fk = lane >> 4;

  for (int k0 = 0; k0 < K; k0 += 64) {
    __syncthreads();
#pragma unroll
    for (int q = 0; q < 2; ++q) {  // A: 16 rows per wave
      int r = wave * 16 + q * 8 + srow;
      int src_slot = sslot ^ (r & 7);
      gload_lds16(A + (size_t)(m0 + r) * K + k0 + src_slot * 8, As + r * 64 + sslot * 8);
    }
#pragma unroll
    for (int q = 0; q < 4; ++q) {  // B: 32 rows per wave
      int r = wave * 32 + q * 8 + srow;
      int src_slot = sslot ^ (r & 7);
      gload_lds16(B + (size_t)(n0 + r) * K + k0 + src_slot * 8, Bs + r * 64 + sslot * 8);
    }
    __syncthreads();

#pragma unroll
    for (int kk = 0; kk < 2; ++kk) {
      short8 af[2], bf[4];
#pragma unroll
      for (int m = 0; m < 2; ++m) {
        int r = wm + m * 16 + fr;
        af[m] = *(const short8*)(As + r * 64 + (((kk * 4 + fk) ^ (r & 7)) << 3));
      }
#pragma unroll
      for (int n = 0; n < 4; ++n) {
        int r = wn + n * 16 + fr;
        bf[n] = *(const short8*)(Bs + r * 64 + (((kk * 4 + fk) ^ (r & 7)) << 3));
      }
#pragma unroll
      for (int m = 0; m < 2; ++m)
#pragma unroll
        for (int n = 0; n < 4; ++n)
          acc[m][n] = __builtin_amdgcn_mfma_f32_16x16x32_bf16(af[m], bf[n], acc[m][n], 0, 0, 0);
    }
  }

  const int fg = lane >> 4;
#pragma unroll
  for (int m = 0; m < 2; ++m)
#pragma unroll
    for (int n = 0; n < 4; ++n)
#pragma unroll
      for (int r = 0; r < 4; ++r) {
        int row = m0 + wm + m * 16 + fg * 4 + r;
        int col = n0 + wn + n * 16 + fr;
        if constexpr (sizeof(OutT) == 2)
          C[(size_t)row * N + col] = (OutT)f2bf(acc[m][n][r]);
        else
          C[(size_t)row * N + col] = (OutT)acc[m][n][r];
      }
}

// ---------------- RoPE v2: one 16B fragment (4 pairs) per thread ----------------
// Q pre-scaled by 0.125*log2(e) (log2-domain softmax downstream).
__global__ __launch_bounds__(256) void rope_qk2(const u16* __restrict__ qkv, const int* __restrict__ pos,
                                                u16* __restrict__ Qf, u16* __restrict__ Kf) {
  int t = blockIdx.x * 256 + threadIdx.x;  // 524288 total
  int l = t & 63;
  int j = (t >> 6) & 3;
  int tile = (t >> 8) & 63;
  int bh = t >> 14;
  int b = bh >> 4, h = bh & 15;
  int s = tile * 32 + (l & 31);
  int dbase = j * 16 + (l >> 5) * 8;
  float p = (float)pos[(b << 11) + s];
  const u16* src = qkv + ((size_t)((b << 11) + s)) * 3072 + h * 64 + dbase;
  uint4 qv = *(const uint4*)src;
  uint4 kv = *(const uint4*)(src + 1024);
  unsigned qin[4] = {qv.x, qv.y, qv.z, qv.w};
  unsigned kin[4] = {kv.x, kv.y, kv.z, kv.w};
  unsigned qo[4], ko[4];
  const float QS = 0.18033688011112043f;  // 0.125 * log2(e)
#pragma unroll
  for (int kp = 0; kp < 4; ++kp) {
    int i = (dbase >> 1) + kp;
    float ang = p * __builtin_exp2f(-(float)i * 0.41524101186f);
    float sn, cs;
    sincosf(ang, &sn, &cs);
    float qe = bf2f((u16)(qin[kp] & 0xffff)), qd = bf2f((u16)(qin[kp] >> 16));
    float ke = bf2f((u16)(kin[kp] & 0xffff)), kd = bf2f((u16)(kin[kp] >> 16));
    qo[kp] = f2bf((cs * qe - sn * qd) * QS) | ((unsigned)f2bf((sn * qe + cs * qd) * QS) << 16);
    ko[kp] = f2bf(cs * ke - sn * kd) | ((unsigned)f2bf(sn * ke + cs * kd) << 16);
  }
  size_t o = ((((size_t)bh * 64 + tile) * 4 + j) * 64 + l) * 8;
  uint4 qw; qw.x = qo[0]; qw.y = qo[1]; qw.z = qo[2]; qw.w = qo[3];
  uint4 kw; kw.x = ko[0]; kw.y = ko[1]; kw.z = ko[2]; kw.w = ko[3];
  *(uint4*)(Qf + o) = qw;
  *(uint4*)(Kf + o) = kw;
}

// ---------------- V pack: qkv V-part -> Vf packed fragment layout ----------------
__global__ __launch_bounds__(256) void v_pack(const u16* __restrict__ qkv, u16* __restrict__ Vf) {
  __shared__ u16 lds[64][72];  // [s_local][d], padded
  const int bh = blockIdx.y;
  const int b = bh >> 4, h = bh & 15;
  const int s0 = blockIdx.x * 64;
  const int t = threadIdx.x;
  {
    const int r = t >> 3;
    const int c = t & 7;
#pragma unroll
    for (int p = 0; p < 2; ++p) {
      int s = r + p * 32;
      const u16* src = qkv + ((size_t)((b << 11) + s0 + s)) * 3072 + 2048 + h * 64 + c * 8;
      *(uint4*)&lds[s][c * 8] = *(const uint4*)src;
    }
  }
  __syncthreads();
#pragma unroll
  for (int p = 0; p < 2; ++p) {
    int item = t + p * 256;
    int tt = item >> 8;
    int seg = (item >> 6) & 3;
    int l = item & 63;
    int d = (seg >> 1) * 32 + (l & 31);
    int sb = tt * 32 + (seg & 1) * 16 + (l >> 5) * 8;
    u16 tmp[8];
#pragma unroll
    for (int e = 0; e < 8; ++e) tmp[e] = lds[sb + e][d];
    int kt = (s0 >> 5) + tt;
    size_t o = ((((size_t)bh * 64 + kt) * 4 + seg) * 64 + l) * 8;
    *(uint4*)(Vf + o) = *(uint4*)tmp;
  }
}

// ---------------- causal flash attention v6: packed-fragment coalesced loads ----------------
__global__ __launch_bounds__(256, 2) void attn6(const u16* __restrict__ Qf, const u16* __restrict__ Kf,
                                                const u16* __restrict__ Vf, u16* __restrict__ Ao) {
  __shared__ float smM[3][64], smL[3][64];
  __shared__ float smO[3][64][33];
  const int tid = threadIdx.x;
  const int lane = tid & 63;
  const int wid = tid >> 6;
  const int bid = blockIdx.x;            // 2048 = 8 xcd * 4 bh * 64 qt
  const int xcd = bid & 7;
  const int rr = bid >> 3;
  const int bh = xcd * 4 + (rr & 3);
  const int qt = 63 - (rr >> 2);
  const int q0 = qt * 32;
  const u16* __restrict__ Qp = Qf + (size_t)bh * 131072;
  const u16* __restrict__ Kp = Kf + (size_t)bh * 131072;
  const u16* __restrict__ Vp = Vf + (size_t)bh * 131072;
  const int lq = lane & 31;
  const int hi = lane >> 5;

  const u16* qb = Qp + (size_t)qt * 2048 + lane * 8;
  short8 qf0 = *(const short8*)(qb);
  short8 qf1 = *(const short8*)(qb + 512);
  short8 qf2 = *(const short8*)(qb + 1024);
  short8 qf3 = *(const short8*)(qb + 1536);

  f32x16 o0, o1;
#pragma unroll
  for (int r = 0; r < 16; ++r) { o0[r] = 0.f; o1[r] = 0.f; }
  float m = -1e30f, lsum = 0.f;

  const int nkt = qt + 1;
  const int base = nkt >> 2, rem = nkt & 3;
  const int cnt = base + (wid < rem ? 1 : 0);
  const int beg = wid * base + (wid < rem ? wid : rem);

  if (cnt > 0) {
    const u16* kp = Kp + (size_t)beg * 2048 + lane * 8;
    const u16* vp = Vp + (size_t)beg * 2048 + lane * 8;
    short8 kc0 = *(const short8*)(kp);
    short8 kc1 = *(const short8*)(kp + 512);
    short8 kc2 = *(const short8*)(kp + 1024);
    short8 kc3 = *(const short8*)(kp + 1536);
    short8 vc0 = *(const short8*)(vp);
    short8 vc1 = *(const short8*)(vp + 512);
    short8 vc2 = *(const short8*)(vp + 1024);
    short8 vc3 = *(const short8*)(vp + 1536);

    for (int i = 0; i < cnt; ++i) {
      const int kt = beg + i;
      const int ktn = beg + (i + 1 < cnt ? i + 1 : i);
      const u16* kpn = Kp + (size_t)ktn * 2048 + lane * 8;
      const u16* vpn = Vp + (size_t)ktn * 2048 + lane * 8;
      short8 kn0 = *(const short8*)(kpn);
      short8 kn1 = *(const short8*)(kpn + 512);
      short8 kn2 = *(const short8*)(kpn + 1024);
      short8 kn3 = *(const short8*)(kpn + 1536);
      short8 vn0 = *(const short8*)(vpn);
      short8 vn1 = *(const short8*)(vpn + 512);
      short8 vn2 = *(const short8*)(vpn + 1024);
      short8 vn3 = *(const short8*)(vpn + 1536);

      f32x16 sc;
#pragma unroll
      for (int r = 0; r < 16; ++r) sc[r] = 0.f;
      sc = __builtin_amdgcn_mfma_f32_32x32x16_bf16(kc0, qf0, sc, 0, 0, 0);
      sc = __builtin_amdgcn_mfma_f32_32x32x16_bf16(kc1, qf1, sc, 0, 0, 0);
      sc = __builtin_amdgcn_mfma_f32_32x32x16_bf16(kc2, qf2, sc, 0, 0, 0);
      sc = __builtin_amdgcn_mfma_f32_32x32x16_bf16(kc3, qf3, sc, 0, 0, 0);

      if (kt == qt) {
#pragma unroll
        for (int r = 0; r < 16; ++r) {
          int ko = (r & 3) + 8 * (r >> 2) + 4 * hi;
          sc[r] = (ko <= lq) ? sc[r] : -1e30f;
        }
      }

      float t0 = fmaxf(fmaxf(sc[0], sc[1]), sc[2]);
      float t1 = fmaxf(fmaxf(sc[3], sc[4]), sc[5]);
      float t2 = fmaxf(fmaxf(sc[6], sc[7]), sc[8]);
      float t3 = fmaxf(fmaxf(sc[9], sc[10]), sc[11]);
      float t4 = fmaxf(fmaxf(sc[12], sc[13]), sc[14]);
      float t5 = fmaxf(fmaxf(t0, t1), sc[15]);
      float t6 = fmaxf(fmaxf(t2, t3), t4);
      float pmax = xhalf_max(fmaxf(t5, t6));

      if (!__all(pmax - m <= 11.5f)) {
        float nm = fmaxf(m, pmax);
        float alpha = __builtin_exp2f(m - nm);
        lsum *= alpha;
#pragma unroll
        for (int r = 0; r < 16; ++r) { o0[r] *= alpha; o1[r] *= alpha; }
        m = nm;
      }

#pragma unroll
      for (int r = 0; r < 16; ++r) sc[r] = __builtin_exp2f(sc[r] - m);
      float r8[8];
#pragma unroll
      for (int r = 0; r < 8; ++r) r8[r] = sc[r] + sc[r + 8];
#pragma unroll
      for (int s = 4; s >= 1; s >>= 1)
#pragma unroll
        for (int r = 0; r < s; ++r) r8[r] += r8[r + s];
      lsum += xhalf_sum(r8[0]);

      unsigned w[8];
#pragma unroll
      for (int t = 0; t < 8; ++t) {
        unsigned d;
        asm("v_cvt_pk_bf16_f32 %0, %1, %2" : "=v"(d) : "v"(sc[2 * t]), "v"(sc[2 * t + 1]));
        w[t] = d;
      }
      short8 pb0, pb1;
      {
        uint2v r1 = __builtin_amdgcn_permlane32_swap(w[0], w[2], false, false);
        uint2v r2 = __builtin_amdgcn_permlane32_swap(w[1], w[3], false, false);
        unsigned r1x = r1.x, r1y = r1.y, r2x = r2.x, r2y = r2.y;
        uint4v t4v; t4v.x = r1x; t4v.y = r2x; t4v.z = r1y; t4v.w = r2y;
        pb0 = __builtin_bit_cast(short8, t4v);
        uint2v r3 = __builtin_amdgcn_permlane32_swap(w[4], w[6], false, false);
        uint2v r4 = __builtin_amdgcn_permlane32_swap(w[5], w[7], false, false);
        unsigned r3x = r3.x, r3y = r3.y, r4x = r4.x, r4y = r4.y;
        uint4v t5v; t5v.x = r3x; t5v.y = r4x; t5v.z = r3y; t5v.w = r4y;
        pb1 = __builtin_bit_cast(short8, t5v);
      }

      o0 = __builtin_amdgcn_mfma_f32_32x32x16_bf16(vc0, pb0, o0, 0, 0, 0);
      o0 = __builtin_amdgcn_mfma_f32_32x32x16_bf16(vc1, pb1, o0, 0, 0, 0);
      o1 = __builtin_amdgcn_mfma_f32_32x32x16_bf16(vc2, pb0, o1, 0, 0, 0);
      o1 = __builtin_amdgcn_mfma_f32_32x32x16_bf16(vc3, pb1, o1, 0, 0, 0);

      kc0 = kn0; kc1 = kn1; kc2 = kn2; kc3 = kn3;
      vc0 = vn0; vc1 = vn1; vc2 = vn2; vc3 = vn3;
    }
  }

  if (wid != 0) {
    smM[wid - 1][lane] = m;
    smL[wid - 1][lane] = lsum;
#pragma unroll
    for (int r = 0; r < 16; ++r) smO[wid - 1][lane][r] = o0[r];
#pragma unroll
    for (int r = 0; r < 16; ++r) smO[wid - 1][lane][16 + r] = o1[r];
  }
  __syncthreads();
  if (wid == 0) {
    float m1 = smM[0][lane], m2 = smM[1][lane], m3 = smM[2][lane];
    float M = fmaxf(fmaxf(m, m1), fmaxf(m2, m3));
    float a0 = __builtin_exp2f(m - M);
    float a1 = __builtin_exp2f(m1 - M);
    float a2 = __builtin_exp2f(m2 - M);
    float a3 = __builtin_exp2f(m3 - M);
    float L = lsum * a0 + smL[0][lane] * a1 + smL[1][lane] * a2 + smL[2][lane] * a3;
    float inv = 1.f / L;
    const int b = bh >> 4, h = bh & 15;
    u16* outp = Ao + ((size_t)(b << 11) + q0 + lq) * 1024 + h * 64;
#pragma unroll
    for (int g = 0; g < 4; ++g) {
      int d = 8 * g + 4 * hi;
      float c[8];
#pragma unroll
      for (int j = 0; j < 4; ++j) {
        c[j] = (o0[4 * g + j] * a0 + smO[0][lane][4 * g + j] * a1 +
                smO[1][lane][4 * g + j] * a2 + smO[2][lane][4 * g + j] * a3) * inv;
        c[4 + j] = (o1[4 * g + j] * a0 + smO[0][lane][16 + 4 * g + j] * a1 +
                    smO[1][lane][16 + 4 * g + j] * a2 + smO[2][lane][16 + 4 * g + j] * a3) * inv;
      }
      uint2v w0;
      w0.x = f2bf(c[0]) | ((unsigned)f2bf(c[1]) << 16);
      w0.y = f2bf(c[2]) | ((unsigned)f2bf(c[3]) << 16);
      *(uint2v*)(outp + d) = w0;
      uint2v w1;
      w1.x = f2bf(c[4]) | ((unsigned)f2bf(c[5]) << 16);
      w1.y = f2bf(c[6]) | ((unsigned)f2bf(c[7]) << 16);
      *(uint2v*)(outp + 32 + d) = w1;
    }
  }
}

extern "C" void kernel_launch(void* const* d_in, const int* in_sizes, int n_in,
                              void* d_out, int out_size, void* d_ws, size_t ws_size,
                              hipStream_t stream) {
  const float* x = (const float*)d_in[0];
  const int* pos = (const int*)d_in[1];
  const float* Wqkv = (const float*)d_in[2];
  const float* Wo = (const float*)d_in[3];
  float* out = (float*)d_out;

  char* ws = (char*)d_ws;
  const size_t MB = 1024 * 1024;
  u16* xb     = (u16*)(ws);             //  8 MB: [4096,1024]
  u16* wqkvb  = (u16*)(ws + 8 * MB);    //  6 MB: [3072,1024]
  u16* wob    = (u16*)(ws + 14 * MB);   //  2 MB: [1024,1024]
  u16* qkv    = (u16*)(ws + 16 * MB);   // 24 MB: [4096,3072]
  u16* Qf     = (u16*)(ws + 40 * MB);   //  8 MB packed fragments (pre-scaled 0.125*log2e)
  u16* Kf     = (u16*)(ws + 48 * MB);   //  8 MB packed fragments
  u16* Vf     = (u16*)(ws + 56 * MB);   //  8 MB packed fragments
  u16* ao     = (u16*)(ws + 64 * MB);   //  8 MB: [4096,1024]

  cvt_all<<<8192, 256, 0, stream>>>(x, Wqkv, Wo, xb, wqkvb, wob);
  gemm_bt2<u16><<<dim3(32, 24), 256, 0, stream>>>(xb, wqkvb, qkv, 4096, 3072, 1024);
  rope_qk2<<<2048, 256, 0, stream>>>(qkv, pos, Qf, Kf);
  v_pack<<<dim3(32, 32), 256, 0, stream>>>(qkv, Vf);
  attn6<<<2048, 256, 0, stream>>>(Qf, Kf, Vf, ao);
  gemm_bt64_2<float><<<dim3(64, 8), 256, 0, stream>>>(ao, wob, out, 4096, 1024, 1024);
}